// Round 1
// baseline (1717.899 us; speedup 1.0000x reference)
//
#include <hip/hip_runtime.h>
#include <hip/hip_bf16.h>
#include <math.h>
#include <stdint.h>

typedef unsigned short u16;
typedef __bf16 bf16x8 __attribute__((ext_vector_type(8)));
typedef float f32x4 __attribute__((ext_vector_type(4)));
typedef __attribute__((address_space(1))) void gv_t;
typedef __attribute__((address_space(3))) void lv_t;

// ---------- helpers ----------
__device__ inline u16 f2bf(float f) {
    union { float f; uint32_t u; } v; v.f = f;
    uint32_t u = v.u;
    uint32_t r = (u + 0x7fffu + ((u >> 16) & 1u)) >> 16;  // RNE
    return (u16)r;
}
__device__ inline float bf2f(u16 h) {
    union { uint32_t u; float f; } v; v.u = ((uint32_t)h) << 16;
    return v.f;
}
__device__ inline float gelu_tanh(float x) {
    // jax.nn.gelu(approximate=True): 0.5x(1+tanh(sqrt(2/pi)(x+0.044715x^3)))
    float u = 0.7978845608028654f * x * (1.0f + 0.044715f * x * x);
    float e = __expf(2.0f * u);
    float t = 1.0f - 2.0f / (e + 1.0f);
    return 0.5f * x * (1.0f + t);
}

// ---------- gate: logits fp32, top-4 of 16, renormalized weights for experts 0..3 ----------
__global__ __launch_bounds__(256) void gate_kernel(const float* __restrict__ x,
                                                   const float* __restrict__ Wg,
                                                   float* __restrict__ w4) {
    const int token = blockIdx.x * 4 + (threadIdx.x >> 6);
    const int lane  = threadIdx.x & 63;
    const float* xr = x + (size_t)token * 1024;
    float acc[16];
#pragma unroll
    for (int e = 0; e < 16; e++) acc[e] = 0.f;
#pragma unroll 4
    for (int d = lane; d < 1024; d += 64) {
        float xv = xr[d];
        const float4* wr_ = (const float4*)(Wg + (size_t)d * 16);
        float4 a0 = wr_[0], a1 = wr_[1], a2 = wr_[2], a3 = wr_[3];
        acc[0]  += xv * a0.x; acc[1]  += xv * a0.y; acc[2]  += xv * a0.z; acc[3]  += xv * a0.w;
        acc[4]  += xv * a1.x; acc[5]  += xv * a1.y; acc[6]  += xv * a1.z; acc[7]  += xv * a1.w;
        acc[8]  += xv * a2.x; acc[9]  += xv * a2.y; acc[10] += xv * a2.z; acc[11] += xv * a2.w;
        acc[12] += xv * a3.x; acc[13] += xv * a3.y; acc[14] += xv * a3.z; acc[15] += xv * a3.w;
    }
#pragma unroll
    for (int e = 0; e < 16; e++) {
        float v = acc[e];
        v += __shfl_xor(v, 32, 64);
        v += __shfl_xor(v, 16, 64);
        v += __shfl_xor(v, 8, 64);
        v += __shfl_xor(v, 4, 64);
        v += __shfl_xor(v, 2, 64);
        v += __shfl_xor(v, 1, 64);
        acc[e] = v;
    }
    if (lane == 0) {
        float l[16];
#pragma unroll
        for (int e = 0; e < 16; e++) l[e] = acc[e];
        int   bi4[4]; float bv4[4];
#pragma unroll
        for (int j = 0; j < 4; j++) {
            int bi = 0; float b = l[0];
#pragma unroll
            for (int e = 1; e < 16; e++) { if (l[e] > b) { b = l[e]; bi = e; } }
            bi4[j] = bi; bv4[j] = b; l[bi] = -INFINITY;
        }
        float mx = bv4[0];
        float den = 0.f;
#pragma unroll
        for (int j = 0; j < 4; j++) den += expf(bv4[j] - mx);
        float wout[4] = {0.f, 0.f, 0.f, 0.f};
#pragma unroll
        for (int j = 0; j < 4; j++)
            if (bi4[j] < 4) wout[bi4[j]] = expf(bv4[j] - mx) / den;
        float* o = w4 + (size_t)token * 4;
        o[0] = wout[0]; o[1] = wout[1]; o[2] = wout[2]; o[3] = wout[3];
    }
}

// ---------- cast x fp32 -> bf16 into Xe[N][1056] (cols >=1024 zeroed; U1 overwritten later) ----------
__global__ void cast_x_kernel(const float* __restrict__ x, u16* __restrict__ Xe) {
    const int n = blockIdx.x;
    for (int c = threadIdx.x; c < 1056; c += 256)
        Xe[(size_t)n * 1056 + c] = (c < 1024) ? f2bf(x[(size_t)n * 1024 + c]) : (u16)0;
}

// ---------- zero He pad cols 4112..4127 ----------
__global__ void hepad_kernel(u16* __restrict__ He) {
    const int n = blockIdx.x;
    if (threadIdx.x < 16) He[(size_t)n * 4128 + 4112 + threadIdx.x] = 0;
}

// ---------- low-rank: out[token][0..15] = bf16( X[token,:] @ Amat[K][16] ) ----------
template<int BF16IN>
__global__ __launch_bounds__(256) void lowrank_kernel(const void* __restrict__ Xin, int ldx,
                                                      const float* __restrict__ Amat,
                                                      u16* __restrict__ outp, int ldo, int K) {
    const int token = blockIdx.x * 4 + (threadIdx.x >> 6);
    const int lane  = threadIdx.x & 63;
    float acc[16];
#pragma unroll
    for (int e = 0; e < 16; e++) acc[e] = 0.f;
    for (int d = lane; d < K; d += 64) {
        float xv;
        if (BF16IN) xv = bf2f(((const u16*)Xin)[(size_t)token * ldx + d]);
        else        xv = ((const float*)Xin)[(size_t)token * ldx + d];
        const float4* ar = (const float4*)(Amat + (size_t)d * 16);
        float4 a0 = ar[0], a1 = ar[1], a2 = ar[2], a3 = ar[3];
        acc[0]  += xv * a0.x; acc[1]  += xv * a0.y; acc[2]  += xv * a0.z; acc[3]  += xv * a0.w;
        acc[4]  += xv * a1.x; acc[5]  += xv * a1.y; acc[6]  += xv * a1.z; acc[7]  += xv * a1.w;
        acc[8]  += xv * a2.x; acc[9]  += xv * a2.y; acc[10] += xv * a2.z; acc[11] += xv * a2.w;
        acc[12] += xv * a3.x; acc[13] += xv * a3.y; acc[14] += xv * a3.z; acc[15] += xv * a3.w;
    }
#pragma unroll
    for (int e = 0; e < 16; e++) {
        float v = acc[e];
        v += __shfl_xor(v, 32, 64);
        v += __shfl_xor(v, 16, 64);
        v += __shfl_xor(v, 8, 64);
        v += __shfl_xor(v, 4, 64);
        v += __shfl_xor(v, 2, 64);
        v += __shfl_xor(v, 1, 64);
        acc[e] = v;
    }
    if (lane == 0) {
        u16* o = outp + (size_t)token * ldo;
#pragma unroll
        for (int r = 0; r < 16; r++) o[r] = f2bf(acc[r]);
    }
}

// ---------- transpose-cast: dst[f][k] = bf16(src[k][f]) ----------
__global__ void tcast_kernel(const float* __restrict__ src, int ldsrc,
                             u16* __restrict__ dst, int lddst) {
    __shared__ float t[32][33];
    const int f0 = blockIdx.x * 32, k0 = blockIdx.y * 32;
    const int tx = threadIdx.x, ty = threadIdx.y;
#pragma unroll
    for (int i = ty; i < 32; i += 8)
        t[i][tx] = src[(size_t)(k0 + i) * ldsrc + f0 + tx];
    __syncthreads();
#pragma unroll
    for (int i = ty; i < 32; i += 8)
        dst[(size_t)(f0 + i) * lddst + k0 + tx] = f2bf(t[tx][i]);
}

// ---------- small cast: dst[f][kbase+r] = bf16(Bm[r][f]) for r<16, zeros r=16..31 ----------
__global__ void smallcast_kernel(const float* __restrict__ Bm, u16* __restrict__ dst,
                                 int lddst, int F, int kbase) {
    int f = blockIdx.x * blockDim.x + threadIdx.x;
    if (f >= F) return;
    u16* o = dst + (size_t)f * lddst + kbase;
#pragma unroll
    for (int r = 0; r < 16; r++) o[r] = f2bf(Bm[(size_t)r * F + f]);
#pragma unroll
    for (int r = 16; r < 32; r++) o[r] = 0;
}

// ---------- main GEMM: C[m][n] = A[M][K] (bf16, lda) x BT[N][K]^T (bf16, ldb) ----------
// EPI 0: Hout[m][n] = bf16(gelu(C))
// EPI 1: Out[m][n]  = w4[m][expert] * C      (store)
// EPI 2: Out[m][n] += w4[m][expert] * C      (accumulate)
template<int EPI>
__global__ __launch_bounds__(256) void gemm_kernel(const u16* __restrict__ A, int lda,
                                                   const u16* __restrict__ BT, int ldb,
                                                   int Ncols, int K,
                                                   u16* __restrict__ Hout, int ldh,
                                                   float* __restrict__ Out, int ldo,
                                                   const float* __restrict__ w4, int expert) {
    __shared__ u16 As[128 * 32];
    __shared__ u16 Bs[128 * 32];
    const int tid  = threadIdx.x;
    const int w    = tid >> 6, lane = tid & 63;
    const int wr   = w >> 1,   wc   = w & 1;
    const int ntn  = Ncols >> 7;
    const int tm   = blockIdx.x / ntn, tn = blockIdx.x % ntn;

    const u16* ag = A  + (size_t)(tm * 128 + (tid >> 2)) * lda + (tid & 3) * 8;
    const u16* bg = BT + (size_t)(tn * 128 + (tid >> 2)) * ldb + (tid & 3) * 8;
    u16* lA0 = &As[w * 512];
    u16* lA1 = &As[(4 + w) * 512];
    u16* lB0 = &Bs[w * 512];
    u16* lB1 = &Bs[(4 + w) * 512];

    f32x4 acc[4][4];
#pragma unroll
    for (int i = 0; i < 4; i++)
#pragma unroll
        for (int j = 0; j < 4; j++)
            acc[i][j] = (f32x4){0.f, 0.f, 0.f, 0.f};

    const int kr = (lane >> 4) * 8;
    const int rA = wr * 64 + (lane & 15);
    const int rB = wc * 64 + (lane & 15);

    const int nk = K >> 5;
    for (int kt = 0; kt < nk; ++kt) {
        __builtin_amdgcn_global_load_lds((gv_t*)(u16*)ag,                      (lv_t*)lA0, 16, 0, 0);
        __builtin_amdgcn_global_load_lds((gv_t*)(u16*)(ag + (size_t)64 * lda), (lv_t*)lA1, 16, 0, 0);
        __builtin_amdgcn_global_load_lds((gv_t*)(u16*)bg,                      (lv_t*)lB0, 16, 0, 0);
        __builtin_amdgcn_global_load_lds((gv_t*)(u16*)(bg + (size_t)64 * ldb), (lv_t*)lB1, 16, 0, 0);
        ag += 32; bg += 32;
        __syncthreads();
        bf16x8 af[4], bv[4];
#pragma unroll
        for (int mi = 0; mi < 4; ++mi)
            af[mi] = *(const bf16x8*)(&As[(rA + mi * 16) * 32 + kr]);
#pragma unroll
        for (int ni = 0; ni < 4; ++ni)
            bv[ni] = *(const bf16x8*)(&Bs[(rB + ni * 16) * 32 + kr]);
#pragma unroll
        for (int mi = 0; mi < 4; ++mi)
#pragma unroll
            for (int ni = 0; ni < 4; ++ni)
                acc[mi][ni] = __builtin_amdgcn_mfma_f32_16x16x32_bf16(af[mi], bv[ni], acc[mi][ni], 0, 0, 0);
        __syncthreads();
    }

    const int rowb = tm * 128 + wr * 64 + ((lane >> 4) << 2);
    const int colb = tn * 128 + wc * 64 + (lane & 15);
    if (EPI == 0) {
#pragma unroll
        for (int mi = 0; mi < 4; ++mi)
#pragma unroll
            for (int r = 0; r < 4; ++r) {
                int m = rowb + mi * 16 + r;
                u16* hrow = Hout + (size_t)m * ldh + colb;
#pragma unroll
                for (int ni = 0; ni < 4; ++ni)
                    hrow[ni * 16] = f2bf(gelu_tanh(acc[mi][ni][r]));
            }
    } else {
#pragma unroll
        for (int mi = 0; mi < 4; ++mi)
#pragma unroll
            for (int r = 0; r < 4; ++r) {
                int m = rowb + mi * 16 + r;
                float wgt = w4[(size_t)m * 4 + expert];
                float* orow = Out + (size_t)m * ldo + colb;
#pragma unroll
                for (int ni = 0; ni < 4; ++ni) {
                    float v = wgt * acc[mi][ni][r];
                    if (EPI == 1) orow[ni * 16] = v;
                    else          orow[ni * 16] += v;
                }
            }
    }
}

// ---------- launch ----------
extern "C" void kernel_launch(void* const* d_in, const int* in_sizes, int n_in,
                              void* d_out, int out_size, void* d_ws, size_t ws_size,
                              hipStream_t stream) {
    (void)in_sizes; (void)n_in; (void)out_size;
    const float* x  = (const float*)d_in[0];
    const float* Wg = (const float*)d_in[1];
    const float* W1 = (const float*)d_in[2];
    const float* A1 = (const float*)d_in[3];
    const float* B1 = (const float*)d_in[4];
    const float* W2 = (const float*)d_in[5];
    const float* A2 = (const float*)d_in[6];
    const float* B2 = (const float*)d_in[7];
    float* out = (float*)d_out;

    const int N = 8192, D = 1024, F = 4096;
    const int KX = 1056, KH = 4128;  // padded K for GEMM1 / GEMM2

    size_t need = (size_t)N * 4 * 4 + (size_t)N * KX * 2 + (size_t)N * KH * 2 +
                  (size_t)F * KX * 2 + (size_t)D * KH * 2;
    if (ws_size < need) return;  // fail visibly (output stays poisoned) rather than corrupt

    char* p = (char*)d_ws;
    float* w4 = (float*)p; p += (size_t)N * 4 * 4;
    u16* Xe   = (u16*)p;   p += (size_t)N * KX * 2;
    u16* He   = (u16*)p;   p += (size_t)N * KH * 2;
    u16* W1T  = (u16*)p;   p += (size_t)F * KX * 2;
    u16* W2T  = (u16*)p;   p += (size_t)D * KH * 2;

    gate_kernel<<<N / 4, 256, 0, stream>>>(x, Wg, w4);
    cast_x_kernel<<<N, 256, 0, stream>>>(x, Xe);
    hepad_kernel<<<N, 64, 0, stream>>>(He);

    for (int e = 0; e < 4; ++e) {
        const float* W1e = W1 + (size_t)e * D * F;
        const float* A1e = A1 + (size_t)e * D * 16;
        const float* B1e = B1 + (size_t)e * 16 * F;
        const float* W2e = W2 + (size_t)e * F * D;
        const float* A2e = A2 + (size_t)e * F * 16;
        const float* B2e = B2 + (size_t)e * 16 * D;

        // U1 = x @ A1[e]  -> Xe cols 1024..1039
        lowrank_kernel<0><<<N / 4, 256, 0, stream>>>((const void*)x, D, A1e, Xe + D, KX, D);
        // W1T[f][k] = W1[e][k][f], B1 appended, padded
        tcast_kernel<<<dim3(F / 32, D / 32), dim3(32, 8), 0, stream>>>(W1e, F, W1T, KX);
        smallcast_kernel<<<(F + 255) / 256, 256, 0, stream>>>(B1e, W1T, KX, F, D);
        // He[:,0..4095] = gelu(Xe @ W1T^T)
        gemm_kernel<0><<<(N / 128) * (F / 128), 256, 0, stream>>>(
            Xe, KX, W1T, KX, F, KX, He, KH, nullptr, 0, nullptr, 0);
        // U2 = H @ A2[e] -> He cols 4096..4111
        lowrank_kernel<1><<<N / 4, 256, 0, stream>>>((const void*)He, KH, A2e, He + F, KH, F);
        // W2T[d][k] = W2[e][k][d], B2 appended, padded
        tcast_kernel<<<dim3(D / 32, F / 32), dim3(32, 8), 0, stream>>>(W2e, D, W2T, KH);
        smallcast_kernel<<<(D + 255) / 256, 256, 0, stream>>>(B2e, W2T, KH, D, F);
        // out (+)= w4[:,e] * (He @ W2T^T)
        if (e == 0)
            gemm_kernel<1><<<(N / 128) * (D / 128), 256, 0, stream>>>(
                He, KH, W2T, KH, D, KH, nullptr, 0, out, D, w4, e);
        else
            gemm_kernel<2><<<(N / 128) * (D / 128), 256, 0, stream>>>(
                He, KH, W2T, KH, D, KH, nullptr, 0, out, D, w4, e);
    }
}

// Round 2
// 895.693 us; speedup vs baseline: 1.9180x; 1.9180x over previous
//
#include <hip/hip_runtime.h>
#include <hip/hip_bf16.h>
#include <math.h>
#include <stdint.h>

typedef unsigned short u16;
typedef __bf16 bf16x8 __attribute__((ext_vector_type(8)));
typedef float f32x4 __attribute__((ext_vector_type(4)));
typedef __attribute__((address_space(1))) void gv_t;
typedef __attribute__((address_space(3))) void lv_t;

// ---------- helpers ----------
__device__ inline u16 f2bf(float f) {
    union { float f; uint32_t u; } v; v.f = f;
    uint32_t u = v.u;
    uint32_t r = (u + 0x7fffu + ((u >> 16) & 1u)) >> 16;  // RNE
    return (u16)r;
}
__device__ inline float gelu_tanh(float x) {
    // jax.nn.gelu(approximate=True)
    float u = 0.7978845608028654f * x * (1.0f + 0.044715f * x * x);
    float e = __expf(2.0f * u);
    float t = 1.0f - 2.0f / (e + 1.0f);
    return 0.5f * x * (1.0f + t);
}

// ---------- gate: logits fp32, top-4 of 16, renormalized weights for experts 0..3 ----------
__global__ __launch_bounds__(256) void gate_kernel(const float* __restrict__ x,
                                                   const float* __restrict__ Wg,
                                                   float* __restrict__ w4) {
    const int token = blockIdx.x * 4 + (threadIdx.x >> 6);
    const int lane  = threadIdx.x & 63;
    const float* xr = x + (size_t)token * 1024;
    float acc[16];
#pragma unroll
    for (int e = 0; e < 16; e++) acc[e] = 0.f;
#pragma unroll 4
    for (int d = lane; d < 1024; d += 64) {
        float xv = xr[d];
        const float4* wr_ = (const float4*)(Wg + (size_t)d * 16);
        float4 a0 = wr_[0], a1 = wr_[1], a2 = wr_[2], a3 = wr_[3];
        acc[0]  += xv * a0.x; acc[1]  += xv * a0.y; acc[2]  += xv * a0.z; acc[3]  += xv * a0.w;
        acc[4]  += xv * a1.x; acc[5]  += xv * a1.y; acc[6]  += xv * a1.z; acc[7]  += xv * a1.w;
        acc[8]  += xv * a2.x; acc[9]  += xv * a2.y; acc[10] += xv * a2.z; acc[11] += xv * a2.w;
        acc[12] += xv * a3.x; acc[13] += xv * a3.y; acc[14] += xv * a3.z; acc[15] += xv * a3.w;
    }
#pragma unroll
    for (int e = 0; e < 16; e++) {
        float v = acc[e];
        v += __shfl_xor(v, 32, 64);
        v += __shfl_xor(v, 16, 64);
        v += __shfl_xor(v, 8, 64);
        v += __shfl_xor(v, 4, 64);
        v += __shfl_xor(v, 2, 64);
        v += __shfl_xor(v, 1, 64);
        acc[e] = v;
    }
    if (lane == 0) {
        float l[16];
#pragma unroll
        for (int e = 0; e < 16; e++) l[e] = acc[e];
        int   bi4[4]; float bv4[4];
#pragma unroll
        for (int j = 0; j < 4; j++) {
            int bi = 0; float b = l[0];
#pragma unroll
            for (int e = 1; e < 16; e++) { if (l[e] > b) { b = l[e]; bi = e; } }
            bi4[j] = bi; bv4[j] = b; l[bi] = -INFINITY;
        }
        float mx = bv4[0];
        float den = 0.f;
#pragma unroll
        for (int j = 0; j < 4; j++) den += expf(bv4[j] - mx);
        float wout[4] = {0.f, 0.f, 0.f, 0.f};
#pragma unroll
        for (int j = 0; j < 4; j++)
            if (bi4[j] < 4) wout[bi4[j]] = expf(bv4[j] - mx) / den;
        float* o = w4 + (size_t)token * 4;
        o[0] = wout[0]; o[1] = wout[1]; o[2] = wout[2]; o[3] = wout[3];
    }
}

// ---------- vectorized cast x fp32 -> bf16 ----------
__global__ __launch_bounds__(256) void cast_x_kernel(const float* __restrict__ x,
                                                     u16* __restrict__ Xe, int nvec) {
    for (int i = blockIdx.x * blockDim.x + threadIdx.x; i < nvec; i += gridDim.x * blockDim.x) {
        const float4* s = (const float4*)(x + (size_t)i * 8);
        float4 a = s[0], b = s[1];
        union { u16 h[8]; uint4 q; } o;
        o.h[0] = f2bf(a.x); o.h[1] = f2bf(a.y); o.h[2] = f2bf(a.z); o.h[3] = f2bf(a.w);
        o.h[4] = f2bf(b.x); o.h[5] = f2bf(b.y); o.h[6] = f2bf(b.z); o.h[7] = f2bf(b.w);
        *(uint4*)(Xe + (size_t)i * 8) = o.q;
    }
}

// ---------- fused transpose + LoRA-fold: dst[f][k] = bf16(src[k][f] + sum_r A[k][r]*B[r][f]) ----------
__global__ __launch_bounds__(256) void weff_kernel(const float* __restrict__ src,
                                                   const float* __restrict__ Am,
                                                   const float* __restrict__ Bm,
                                                   u16* __restrict__ dst,
                                                   int Fdim, int lddst,
                                                   size_t s_est, size_t a_est, size_t b_est, size_t d_est) {
    const int e = blockIdx.z;
    src += e * s_est; Am += e * a_est; Bm += e * b_est; dst += e * d_est;
    __shared__ float t[32][33];
    __shared__ float sa[32][16];
    __shared__ float sb[16][32];
    const int tx = threadIdx.x, ty = threadIdx.y, tid = ty * 32 + tx;
    const int f0 = blockIdx.x * 32, k0 = blockIdx.y * 32;
#pragma unroll
    for (int i = ty; i < 32; i += 8) t[i][tx] = src[(size_t)(k0 + i) * Fdim + f0 + tx];
    for (int idx = tid; idx < 512; idx += 256) sa[idx >> 4][idx & 15] = Am[(size_t)(k0 + (idx >> 4)) * 16 + (idx & 15)];
    for (int idx = tid; idx < 512; idx += 256) sb[idx >> 5][idx & 31] = Bm[(size_t)(idx >> 5) * Fdim + f0 + (idx & 31)];
    __syncthreads();
#pragma unroll
    for (int i = ty; i < 32; i += 8) {
        float s = t[tx][i];
#pragma unroll
        for (int r = 0; r < 16; r++) s += sa[tx][r] * sb[r][i];
        dst[(size_t)(f0 + i) * lddst + k0 + tx] = f2bf(s);
    }
}

// ---------- deep-pipelined GEMM: C = A[M][K] @ BT[N][K]^T, BM=256, BK=64, 8 waves ----------
// EPI 0: Hout[m][n] = bf16(w4[m][tn>>4] * gelu(C))   (GEMM1, BN=256)
// EPI 1: Out[m][n]  = C (fp32 store)                 (GEMM2, BN=128)
template<int BN, int EPI>
__global__ __launch_bounds__(512, 2) void gemm8p_kernel(
    const u16* __restrict__ A, const u16* __restrict__ BT,
    const int lda, const int ldb, const int ntn, const int NT,
    u16* __restrict__ Hout, const int ldh, const float* __restrict__ w4,
    float* __restrict__ Out, const int ldo) {
    constexpr int NF  = BN / 64;   // n-frags per wave
    constexpr int NBS = BN / 64;   // B staging sweeps per K-tile
    constexpr int NS  = 4 + NBS;   // total staging sweeps per K-tile
    constexpr int NSH = (NS + 1) / 2;
    __shared__ __align__(16) u16 As[2][256 * 64];
    __shared__ __align__(16) u16 Bs[2][BN * 64];

    const int tid = threadIdx.x;
    const int w = tid >> 6, lane = tid & 63;
    const int wr = w >> 2, wc = w & 3;

    // bijective XCD chunked swizzle (gridDim.x % 8 == 0)
    const int chunk = gridDim.x >> 3;
    const int swz = (blockIdx.x & 7) * chunk + (blockIdx.x >> 3);
    const int tm = swz / ntn, tn = swz % ntn;

    // staging: sweep covers 64 rows; wave w -> rows w*8..w*8+7, lane chunk XOR-preswizzled
    const int srow = w * 8 + (lane >> 3);
    const int schunk = ((lane & 7) ^ ((lane >> 3) & 7)) * 8;
    const u16* gA = A  + (size_t)(tm * 256 + srow) * lda + schunk;
    const u16* gB = BT + (size_t)(tn * BN  + srow) * ldb + schunk;
    const int ldsw = w * 512;

    // fragment read bases (element units; row stride 64 el = 128 B)
    const int rowA = (wr * 128 + (lane & 15)) * 64;
    const int rowB = (wc * (BN / 4) + (lane & 15)) * 64;
    const int lsw = lane & 7, kq = lane >> 4;
    const int koff0 = ((kq ^ lsw) << 3);
    const int koff1 = (((4 + kq) ^ lsw) << 3);

    f32x4 acc[8][NF];
#pragma unroll
    for (int m = 0; m < 8; m++)
#pragma unroll
        for (int n = 0; n < NF; n++) acc[m][n] = (f32x4){0.f, 0.f, 0.f, 0.f};

    auto stage = [&](int i, int bufn, int tcol) {
        if (i < 4)
            __builtin_amdgcn_global_load_lds((gv_t*)(u16*)(gA + (size_t)(i * 64) * lda + tcol),
                                             (lv_t*)&As[bufn][i * 4096 + ldsw], 16, 0, 0);
        else
            __builtin_amdgcn_global_load_lds((gv_t*)(u16*)(gB + (size_t)((i - 4) * 64) * ldb + tcol),
                                             (lv_t*)&Bs[bufn][(i - 4) * 4096 + ldsw], 16, 0, 0);
    };

    // prologue: stage tile 0 -> buf 0
#pragma unroll
    for (int i = 0; i < NS; i++) stage(i, 0, 0);
    asm volatile("s_waitcnt vmcnt(0)" ::: "memory");
    __builtin_amdgcn_s_barrier();
    __builtin_amdgcn_sched_barrier(0);

    for (int t = 0; t < NT; ++t) {
        const int buf = t & 1;
        const int pcol = (t + 1) * 64;
        const bool pf = (t + 1 < NT);
        bf16x8 af[8], bv[NF];
        // ---- phase 0 (k 0..31) ----
#pragma unroll
        for (int m = 0; m < 8; m++) af[m] = *(const bf16x8*)&As[buf][rowA + m * 1024 + koff0];
#pragma unroll
        for (int n = 0; n < NF; n++) bv[n] = *(const bf16x8*)&Bs[buf][rowB + n * 1024 + koff0];
        if (pf) {
#pragma unroll
            for (int i = 0; i < NSH; i++) stage(i, buf ^ 1, pcol);
        }
        __builtin_amdgcn_s_barrier();
        asm volatile("s_waitcnt lgkmcnt(0)" ::: "memory");
        __builtin_amdgcn_sched_barrier(0);
        __builtin_amdgcn_s_setprio(1);
#pragma unroll
        for (int m = 0; m < 8; m++)
#pragma unroll
            for (int n = 0; n < NF; n++)
                acc[m][n] = __builtin_amdgcn_mfma_f32_16x16x32_bf16(af[m], bv[n], acc[m][n], 0, 0, 0);
        __builtin_amdgcn_s_setprio(0);
        // ---- phase 1 (k 32..63) ----
#pragma unroll
        for (int m = 0; m < 8; m++) af[m] = *(const bf16x8*)&As[buf][rowA + m * 1024 + koff1];
#pragma unroll
        for (int n = 0; n < NF; n++) bv[n] = *(const bf16x8*)&Bs[buf][rowB + n * 1024 + koff1];
        if (pf) {
#pragma unroll
            for (int i = NSH; i < NS; i++) stage(i, buf ^ 1, pcol);
        }
        __builtin_amdgcn_s_barrier();
        asm volatile("s_waitcnt lgkmcnt(0)" ::: "memory");
        __builtin_amdgcn_sched_barrier(0);
        __builtin_amdgcn_s_setprio(1);
#pragma unroll
        for (int m = 0; m < 8; m++)
#pragma unroll
            for (int n = 0; n < NF; n++)
                acc[m][n] = __builtin_amdgcn_mfma_f32_16x16x32_bf16(af[m], bv[n], acc[m][n], 0, 0, 0);
        __builtin_amdgcn_s_setprio(0);
        // ---- boundary: tile t+1 fully staged, drain once per K-tile ----
        if (pf) asm volatile("s_waitcnt vmcnt(0)" ::: "memory");
        __builtin_amdgcn_s_barrier();
        __builtin_amdgcn_sched_barrier(0);
    }

    // ---- epilogue ----
    const int rbase = tm * 256 + wr * 128 + kq * 4;
    const int cbase = tn * BN + wc * (BN / 4) + (lane & 15);
    if (EPI == 0) {
        const int e = tn >> 4;  // 4096-wide expert blocks, BN=256 -> 16 tiles/expert
#pragma unroll
        for (int m = 0; m < 8; m++) {
#pragma unroll
            for (int r = 0; r < 4; r++) {
                const int row = rbase + m * 16 + r;
                const float wgt = w4[(size_t)row * 4 + e];
                u16* hp = Hout + (size_t)row * ldh + cbase;
#pragma unroll
                for (int n = 0; n < NF; n++)
                    hp[n * 16] = f2bf(wgt * gelu_tanh(acc[m][n][r]));
            }
        }
    } else {
#pragma unroll
        for (int m = 0; m < 8; m++) {
#pragma unroll
            for (int r = 0; r < 4; r++) {
                const int row = rbase + m * 16 + r;
                float* op = Out + (size_t)row * ldo + cbase;
#pragma unroll
                for (int n = 0; n < NF; n++) op[n * 16] = acc[m][n][r];
            }
        }
    }
}

// ---------- launch ----------
extern "C" void kernel_launch(void* const* d_in, const int* in_sizes, int n_in,
                              void* d_out, int out_size, void* d_ws, size_t ws_size,
                              hipStream_t stream) {
    (void)in_sizes; (void)n_in; (void)out_size;
    const float* x  = (const float*)d_in[0];
    const float* Wg = (const float*)d_in[1];
    const float* W1 = (const float*)d_in[2];
    const float* A1 = (const float*)d_in[3];
    const float* B1 = (const float*)d_in[4];
    const float* W2 = (const float*)d_in[5];
    const float* A2 = (const float*)d_in[6];
    const float* B2 = (const float*)d_in[7];
    float* out = (float*)d_out;

    const int N = 8192;

    const size_t need = 131072
                      + (size_t)8192 * 1024 * 2
                      + (size_t)8192 * 16384 * 2
                      + (size_t)16384 * 1024 * 2
                      + (size_t)1024 * 16384 * 2;
    if (ws_size < need) return;  // fail visibly rather than corrupt

    char* p = (char*)d_ws;
    float* w4 = (float*)p; p += 131072;
    u16* Xe   = (u16*)p;   p += (size_t)8192 * 1024 * 2;
    u16* Hs   = (u16*)p;   p += (size_t)8192 * 16384 * 2;
    u16* W1T  = (u16*)p;   p += (size_t)16384 * 1024 * 2;
    u16* W2T  = (u16*)p;   p += (size_t)1024 * 16384 * 2;

    gate_kernel<<<N / 4, 256, 0, stream>>>(x, Wg, w4);
    cast_x_kernel<<<2048, 256, 0, stream>>>(x, Xe, N * 1024 / 8);
    // W1eff^T[e*4096+f][k] = bf16(W1[e][k][f] + sum_r A1[e][k][r]*B1[e][r][f])
    weff_kernel<<<dim3(128, 32, 4), dim3(32, 8), 0, stream>>>(
        W1, A1, B1, W1T, 4096, 1024,
        (size_t)1024 * 4096, (size_t)1024 * 16, (size_t)16 * 4096, (size_t)4096 * 1024);
    // W2eff^T[d][e*4096+k] = bf16(W2[e][k][d] + sum_r A2[e][k][r]*B2[e][r][d])
    weff_kernel<<<dim3(32, 128, 4), dim3(32, 8), 0, stream>>>(
        W2, A2, B2, W2T, 1024, 16384,
        (size_t)4096 * 1024, (size_t)4096 * 16, (size_t)16 * 1024, (size_t)4096);
    // Hs[m][e*4096+f] = bf16(w4[m][e] * gelu(Xe @ W1eff^T))
    gemm8p_kernel<256, 0><<<(N / 256) * 64, 512, 0, stream>>>(
        Xe, W1T, 1024, 1024, 64, 16, Hs, 16384, w4, nullptr, 0);
    // out = Hs @ W2eff^T   (w already folded into Hs; K = 16384 spans all 4 experts)
    gemm8p_kernel<128, 1><<<(N / 256) * 8, 512, 0, stream>>>(
        Hs, W2T, 16384, 16384, 8, 256, nullptr, 0, nullptr, out, 1024);
}